// Round 2
// 1387.387 us; speedup vs baseline: 2.1818x; 2.1818x over previous
//
#include <hip/hip_runtime.h>
#include <hip/hip_bf16.h>

typedef __hip_bfloat16 bf16;
typedef __attribute__((ext_vector_type(8))) short short8;
typedef __attribute__((ext_vector_type(4))) float float4v;

#define TPB 256

__device__ __forceinline__ short f2bs(float v) {
    __hip_bfloat16 h = __float2bfloat16(v);
    return *reinterpret_cast<short*>(&h);
}
__device__ __forceinline__ float bs2f(short s) {
    union { unsigned u; float f; } c; c.u = ((unsigned)(unsigned short)s) << 16; return c.f;
}
__device__ __forceinline__ short ldbits(const bf16* p, size_t i)  { return ((const short*)p)[i]; }
__device__ __forceinline__ short ldbits(const float* p, size_t i) { return f2bs(p[i]); }
__device__ __forceinline__ void stf(float* p, size_t i, float v) { p[i] = v; }
__device__ __forceinline__ void stf(bf16* p, size_t i, float v)  { p[i] = __float2bfloat16(v); }

// async global->LDS DMA, 16B per lane; LDS dest = wave-uniform base + lane*16
__device__ __forceinline__ void gl_lds16(const void* g, void* l) {
    __builtin_amdgcn_global_load_lds(
        (const __attribute__((address_space(1))) void*)g,
        (__attribute__((address_space(3))) void*)l, 16, 0, 0);
}

// ---------------------------------------------------------------------------
// Weight pre-transform: (Cout, Cin, K, K) f32 -> bf16 [nb][cb][tap][nn(64)][ci(40)]
// ci padded 32->40 WITH ZEROS so the conv-side LDS image (row stride 40 shorts,
// the conflict-free stride) is a pure linear copy of global memory -> staging
// is global_load_lds DMA with zero VALU and zero bank conflicts.
// ---------------------------------------------------------------------------
__global__ void wxform_kernel(const float* __restrict__ w, bf16* __restrict__ dst,
                              int Cin, int taps, int total) {
    int i = blockIdx.x * TPB + threadIdx.x;
    if (i >= total) return;
    int nc = Cin >> 5;
    int ci = i % 40;
    int r  = i / 40;
    int nn = r & 63; r >>= 6;
    int tap = r % taps; r /= taps;
    int cb = r % nc;
    int nb = r / nc;
    float v = (ci < 32)
        ? w[((size_t)(nb * 64 + nn) * Cin + (cb * 32 + ci)) * taps + tap] : 0.f;
    dst[i] = __float2bfloat16(v);
}

// obj_maps f32 -> bf16 (one-time; numerics identical to per-conv f2bs staging)
__global__ void cvt_kernel(const float* __restrict__ src, bf16* __restrict__ dst, int n8) {
    int i = blockIdx.x * TPB + threadIdx.x;
    if (i >= n8) return;
    const float4v* s = (const float4v*)src;
    float4v a = s[i * 2], b = s[i * 2 + 1];
    short8 o;
#pragma unroll
    for (int j = 0; j < 4; ++j) { o[j] = f2bs(a[j]); o[4 + j] = f2bs(b[j]); }
    *(short8*)(dst + (size_t)i * 8) = o;
}

// ---------------------------------------------------------------------------
// MFMA implicit-GEMM conv (KxK, pad K/2) + fused instance-norm + leaky-relu.
// 1-D grid, XCD-swizzled image-major: unit u -> (n = u/NCB, n0 = (u%NCB)*64).
// Per block: M=256 spatial x N=64 outch, 4 waves (wave w: rows [w*64,w*64+64)).
// K-loop: Cin chunks of 32. B staged by global_load_lds DMA from the
// pre-transformed padded bf16 weights (linear copy, stride-40 rows ->
// conflict-free b128 reads). A staged as short8 ds_write_b128 (stride-40,
// conflict-free). MODE 0: norm+act -> out. MODE 1: norm+act, out += (f32).
// MODE 2 (conv1b): n0<128 raw->out_s(bf16); 128..255 norm+act->out(f32); else raw->out_o.
// GATHER: input = concat(obj[s], pred bcast, obj[o]) per edge.
// ---------------------------------------------------------------------------
template<int K, int MODE, bool GATHER, int NCB, typename TIN, typename TOUT>
__global__ __launch_bounds__(TPB, 2) void mconv_kernel(
    const TIN* __restrict__ in,
    const float* __restrict__ pred_vecs,
    const int*  __restrict__ edges,
    const bf16* __restrict__ wbf,    // pre-transformed [nb][cb][tap][64][40] bf16
    const float* __restrict__ bfp,   // (Cout) f32
    TOUT* __restrict__ out,
    bf16* __restrict__ out_s,
    bf16* __restrict__ out_o,
    int Cin, int Cout)
{
    constexpr int P    = K / 2;
    constexpr int W    = 16 + 2 * P;       // padded tile width
    constexpr int TAPS = K * K;
    constexpr int CS   = 40;               // channel stride: 80B rows, dword-stride 20 -> conflict-free

    __shared__ __align__(16) short Ash[W * W * CS];      // input chunk, pixel-major
    __shared__ __align__(16) short Bsh[TAPS * 64 * CS];  // weights [tap][n][ci40], linear DMA image
    __shared__ float redS[256], redS2[256];

    const int tid  = threadIdx.x;
    const int lane = tid & 63;
    const int wv   = tid >> 6;
    const int quad = lane >> 4;
    const int l16  = lane & 15;

    // XCD-aware swizzle: each of 8 XCDs takes a contiguous, image-major chunk.
    const int d = blockIdx.x;
    const int u = (d & 7) * (gridDim.x >> 3) + (d >> 3);
    const int n  = u / NCB;
    const int n0 = (u - n * NCB) * 64;

    // zero A buffer once (border + pad columns stay 0 forever)
    for (int i = tid; i < W * W * CS / 2; i += TPB) ((int*)Ash)[i] = 0;

    // acc init with bias (C-layout: col=n depends only on l16)
    float4v acc[4][4];
#pragma unroll
    for (int nt = 0; nt < 4; ++nt) {
        float b = bfp[n0 + nt * 16 + l16];
#pragma unroll
        for (int mt = 0; mt < 4; ++mt) acc[mt][nt] = float4v{b, b, b, b};
    }

    int s_idx = 0, o_idx = 0;
    if (GATHER) { s_idx = edges[2 * n]; o_idx = edges[2 * n + 1]; }

    const int y0 = tid >> 4, x0 = tid & 15;                 // staging pixel = tid
    const int abase = ((y0 + P) * W + (x0 + P)) * CS;
    const int nc = Cin >> 5;

    for (int cc0 = 0; cc0 < Cin; cc0 += 32) {
        __syncthreads();

        // ---- stage B: async DMA, linear copy of TAPS*5120B slice ----
        const char* wsrc = (const char*)wbf +
            ((size_t)(n0 >> 6) * nc + (cc0 >> 5)) * (size_t)(TAPS * 64 * CS * 2);
        for (int k = wv; k < TAPS * 5; k += 4)
            gl_lds16(wsrc + (k << 10) + (lane << 4), (char*)Bsh + (k << 10));

        // ---- stage A: 32 ch x 256 pix, short8-packed, one b128 write / 8ch ----
#pragma unroll
        for (int c8 = 0; c8 < 4; ++c8) {
            short8 pk;
#pragma unroll
            for (int j = 0; j < 8; ++j) {
                const int gc = cc0 + c8 * 8 + j;
                short s;
                if (GATHER) {
                    if (gc < 64)
                        s = ldbits(in, (size_t)s_idx * 16384 + (size_t)gc * 256 + tid);
                    else if (gc < 128)
                        s = f2bs(pred_vecs[n * 64 + (gc - 64)]);
                    else
                        s = ldbits(in, (size_t)o_idx * 16384 + (size_t)(gc - 128) * 256 + tid);
                } else {
                    s = ldbits(in, ((size_t)n * Cin + gc) * 256 + tid);
                }
                pk[j] = s;
            }
            *(short8*)&Ash[abase + c8 * 8] = pk;
        }
        __syncthreads();   // drains vmcnt (DMA) + lgkm before compute

        // ---- compute: taps x (4 B-frags, 4x4 MFMA) ----
#pragma unroll 1
        for (int tap = 0; tap < TAPS; ++tap) {
            const int dy = (K == 3) ? tap / 3 : 0;
            const int dx = (K == 3) ? tap - dy * 3 : 0;
            short8 bfr[4];
#pragma unroll
            for (int nt = 0; nt < 4; ++nt)
                bfr[nt] = *(const short8*)&Bsh[(tap * 64 + nt * 16 + l16) * CS + quad * 8];
#pragma unroll
            for (int mt = 0; mt < 4; ++mt) {
                const int m = (wv << 6) + mt * 16 + l16;
                const int pix = ((m >> 4) + dy) * W + ((m & 15) + dx);
                short8 afr = *(const short8*)&Ash[pix * CS + quad * 8];
#pragma unroll
                for (int nt = 0; nt < 4; ++nt)
                    acc[mt][nt] = __builtin_amdgcn_mfma_f32_16x16x32_bf16(
                        afr, bfr[nt], acc[mt][nt], 0, 0, 0);
            }
        }
    }

    // ---------------- epilogue ----------------
    const bool do_norm = (MODE == 2) ? (n0 >= 128 && n0 < 256) : true;
    float mean[4], rstd[4];
    if (do_norm) {
#pragma unroll
        for (int nt = 0; nt < 4; ++nt) {
            float s = 0.f, s2 = 0.f;
#pragma unroll
            for (int mt = 0; mt < 4; ++mt)
#pragma unroll
                for (int r = 0; r < 4; ++r) {
                    float v = acc[mt][nt][r];
                    s += v; s2 += v * v;
                }
            s  += __shfl_xor(s, 16, 64);  s  += __shfl_xor(s, 32, 64);
            s2 += __shfl_xor(s2, 16, 64); s2 += __shfl_xor(s2, 32, 64);
            if (quad == 0) {
                redS [wv * 64 + nt * 16 + l16] = s;
                redS2[wv * 64 + nt * 16 + l16] = s2;
            }
        }
        __syncthreads();
#pragma unroll
        for (int nt = 0; nt < 4; ++nt) {
            int c = nt * 16 + l16;
            float s  = redS [c] + redS [64 + c] + redS [128 + c] + redS [192 + c];
            float s2 = redS2[c] + redS2[64 + c] + redS2[128 + c] + redS2[192 + c];
            float m  = s * (1.f / 256.f);
            float var = s2 * (1.f / 256.f) - m * m;
            mean[nt] = m;
            rstd[nt] = rsqrtf(var + 1e-5f);
        }
    }

    // LDS-transpose store, 16 channels at a time.
    // Stride 261: write conflicts ~2-way (free); interleaved pixel read
    // (thread = (ch16, p16), pixels p16+16i) keeps stores coalesced, reads <=4-way.
    float* Tb = (float*)Ash;
    const int ch16 = tid >> 4;
    const int p16  = tid & 15;
#pragma unroll 1
    for (int nt = 0; nt < 4; ++nt) {
        __syncthreads();
#pragma unroll
        for (int mt = 0; mt < 4; ++mt)
#pragma unroll
            for (int r = 0; r < 4; ++r) {
                float v = acc[mt][nt][r];
                if (do_norm) {
                    v = (v - mean[nt]) * rstd[nt];
                    v = (v >= 0.f) ? v : 0.1f * v;
                }
                Tb[l16 * 261 + (wv << 6) + mt * 16 + (quad << 2) + r] = v;
            }
        __syncthreads();
        const float* Tp = &Tb[ch16 * 261 + p16];
        const int gch = n0 + nt * 16 + ch16;
        if (MODE == 2) {
            if (n0 < 128) {
                bf16* dst = out_s + ((size_t)n * 128 + gch) * 256 + p16;
#pragma unroll
                for (int i = 0; i < 16; ++i) dst[i * 16] = __float2bfloat16(Tp[i * 16]);
            } else if (n0 < 256) {
                float* dst = (float*)out + ((size_t)n * 128 + (gch - 128)) * 256 + p16;
#pragma unroll
                for (int i = 0; i < 16; ++i) dst[i * 16] = Tp[i * 16];
            } else {
                bf16* dst = out_o + ((size_t)n * 128 + (gch - 256)) * 256 + p16;
#pragma unroll
                for (int i = 0; i < 16; ++i) dst[i * 16] = __float2bfloat16(Tp[i * 16]);
            }
        } else if (MODE == 1) {
            float* dst = (float*)out + ((size_t)n * Cout + gch) * 256 + p16;
#pragma unroll
            for (int i = 0; i < 16; ++i) dst[i * 16] = dst[i * 16] + Tp[i * 16];
        } else {
            TOUT* dst = out + ((size_t)n * Cout + gch) * 256 + p16;
#pragma unroll
            for (int i = 0; i < 16; ++i) stf(dst, (size_t)i * 16, Tp[i * 16]);
        }
    }
}

// ---------------------------------------------------------------------------
// Deterministic segment-mean pooling, short8-vectorized.
// ---------------------------------------------------------------------------
__global__ __launch_bounds__(TPB) void pool_kernel(
    const int* __restrict__ edges,
    const bf16* __restrict__ new_s,
    const bf16* __restrict__ new_o,
    bf16* __restrict__ pooled)
{
    const int ob  = blockIdx.x;
    const int tid = threadIdx.x;
    __shared__ int list[2048];
    __shared__ int cnt;
    if (tid == 0) cnt = 0;
    __syncthreads();
    for (int t = tid; t < 1024; t += TPB) {
        int si = edges[2 * t], oi = edges[2 * t + 1];
        if (si == ob) { int p = atomicAdd(&cnt, 1); list[p] = t * 2; }
        if (oi == ob) { int p = atomicAdd(&cnt, 1); list[p] = t * 2 + 1; }
    }
    __syncthreads();
    const int c = cnt;
    const float inv = 1.f / fmaxf((float)c, 1.f);
    for (int e8 = tid; e8 < 4096; e8 += TPB) {          // 32768 elems / 8
        float s[8] = {0.f, 0.f, 0.f, 0.f, 0.f, 0.f, 0.f, 0.f};
        for (int m = 0; m < c; ++m) {
            int ent = list[m];
            int nn  = ent >> 1;
            const bf16* src = (ent & 1) ? new_o : new_s;
            short8 v = *(const short8*)(src + (size_t)nn * 32768 + (size_t)e8 * 8);
#pragma unroll
            for (int j = 0; j < 8; ++j) s[j] += bs2f(v[j]);
        }
        short8 o;
#pragma unroll
        for (int j = 0; j < 8; ++j) o[j] = f2bs(s[j] * inv);
        *(short8*)(pooled + (size_t)ob * 32768 + (size_t)e8 * 8) = o;
    }
}

// ---------------------------------------------------------------------------
extern "C" void kernel_launch(void* const* d_in, const int* in_sizes, int n_in,
                              void* d_out, int out_size, void* d_ws, size_t ws_size,
                              hipStream_t stream) {
    const float* obj_maps  = (const float*)d_in[0];   // (512,64,16,16) f32
    const float* pred_vecs = (const float*)d_in[1];   // (1024,64) f32
    const int*   edges     = (const int*)d_in[2];     // (1024,2) i32
    const float* w1a = (const float*)d_in[4];  const float* b1a = (const float*)d_in[5];
    const float* w1b = (const float*)d_in[6];  const float* b1b = (const float*)d_in[7];
    const float* w2a = (const float*)d_in[8];  const float* b2a = (const float*)d_in[9];
    const float* w2b = (const float*)d_in[10]; const float* b2b = (const float*)d_in[11];
    const float* woa = (const float*)d_in[12]; const float* boa = (const float*)d_in[13];
    const float* wob = (const float*)d_in[14]; const float* bob = (const float*)d_in[15];

    float* out = (float*)d_out;                       // [new_obj | new_p] f32
    const size_t NP_OFF = (size_t)512 * 128 * 256;

    char* ws = (char*)d_ws;
    size_t off = 0;
    auto alloc = [&](size_t bytes) -> char* {
        char* p = ws + off;
        off += (bytes + 255) & ~(size_t)255;
        return p;
    };
    const size_t SZ_T = (size_t)1024 * 128 * 256 * 2;   // 67 MB
    char* Bt1   = alloc(SZ_T);
    char* Bnews = alloc(SZ_T);
    char* Bnewo = alloc(SZ_T);
    // padded weight images: (Cout/64)*(Cin/32)*taps*64*40 bf16
    auto wsz = [](int Cout, int Cin, int taps) -> size_t {
        return (size_t)(Cout / 64) * (Cin / 32) * taps * 64 * 40 * 2;
    };
    bf16* wb1a = (bf16*)alloc(wsz(128, 192, 9));
    bf16* wb1b = (bf16*)alloc(wsz(384, 128, 9));
    bf16* wb2a = (bf16*)alloc(wsz(128, 128, 9));
    bf16* wb2b = (bf16*)alloc(wsz(128, 128, 1));
    bf16* wboa = (bf16*)alloc(wsz(128,  64, 9));
    bf16* wbob = (bf16*)alloc(wsz(128, 128, 1));
    // optional bf16 obj_maps cache (guarded by ws_size; fall back to f32 reads)
    const size_t OBJ_SZ = (size_t)512 * 64 * 256 * 2;   // 16.8 MB
    bf16* obj_bf = (bf16*)alloc(OBJ_SZ);
    const bool use_objbf = (off <= ws_size);

    bf16* t1     = (bf16*)Bt1;
    bf16* new_s  = (bf16*)Bnews;
    bf16* new_o  = (bf16*)Bnewo;
    bf16* pooled = (bf16*)Bt1;                                   // t1 dead after conv1b
    bf16* u1     = (bf16*)(Bt1 + (size_t)512 * 128 * 256 * 2);
    bf16* v1     = (bf16*)Bnews;                                 // new_s dead after pool

    // ---- one-time prep: weights -> padded bf16 DMA layout; obj_maps -> bf16 ----
    auto wx = [&](const float* w, bf16* dw, int Cout, int Cin, int taps) {
        int total = (Cout / 64) * (Cin / 32) * taps * 64 * 40;
        wxform_kernel<<<dim3((total + TPB - 1) / TPB), dim3(TPB), 0, stream>>>(
            w, dw, Cin, taps, total);
    };
    wx(w1a, wb1a, 128, 192, 9);
    wx(w1b, wb1b, 384, 128, 9);
    wx(w2a, wb2a, 128, 128, 9);
    wx(w2b, wb2b, 128, 128, 1);
    wx(woa, wboa, 128,  64, 9);
    wx(wob, wbob, 128, 128, 1);
    if (use_objbf)
        cvt_kernel<<<dim3(4096), dim3(TPB), 0, stream>>>(obj_maps, obj_bf, 512 * 64 * 256 / 8);

    // conv1a: gather(192) -> 128, 3x3, norm+act -> t1 (bf16)
    if (use_objbf)
        mconv_kernel<3, 0, true, 2, bf16, bf16><<<dim3(2048), dim3(TPB), 0, stream>>>(
            obj_bf, pred_vecs, edges, wb1a, b1a, t1, nullptr, nullptr, 192, 128);
    else
        mconv_kernel<3, 0, true, 2, float, bf16><<<dim3(2048), dim3(TPB), 0, stream>>>(
            obj_maps, pred_vecs, edges, wb1a, b1a, t1, nullptr, nullptr, 192, 128);

    // conv1b: t1 128 -> 384, 3x3; split new_s / new_p(norm+act, f32 d_out) / new_o
    mconv_kernel<3, 2, false, 6, bf16, float><<<dim3(6144), dim3(TPB), 0, stream>>>(
        t1, nullptr, nullptr, wb1b, b1b, out + NP_OFF, new_s, new_o, 128, 384);

    // segment-mean pooling -> pooled (512,128,16,16) bf16
    pool_kernel<<<dim3(512), dim3(TPB), 0, stream>>>(edges, new_s, new_o, pooled);

    // conv2a: pooled 128 -> 128, 3x3, norm+act -> u1 (bf16)
    mconv_kernel<3, 0, false, 2, bf16, bf16><<<dim3(1024), dim3(TPB), 0, stream>>>(
        pooled, nullptr, nullptr, wb2a, b2a, u1, nullptr, nullptr, 128, 128);

    // conv2b: u1 128 -> 128, 1x1, norm+act -> d_out[new_obj] (overwrite)
    mconv_kernel<1, 0, false, 2, bf16, float><<<dim3(1024), dim3(TPB), 0, stream>>>(
        u1, nullptr, nullptr, wb2b, b2b, out, nullptr, nullptr, 128, 128);

    // convoa: obj 64 -> 128, 3x3, norm+act -> v1 (bf16)
    if (use_objbf)
        mconv_kernel<3, 0, false, 2, bf16, bf16><<<dim3(1024), dim3(TPB), 0, stream>>>(
            obj_bf, nullptr, nullptr, wboa, boa, v1, nullptr, nullptr, 64, 128);
    else
        mconv_kernel<3, 0, false, 2, float, bf16><<<dim3(1024), dim3(TPB), 0, stream>>>(
            obj_maps, nullptr, nullptr, wboa, boa, v1, nullptr, nullptr, 64, 128);

    // convob: v1 128 -> 128, 1x1, norm+act, d_out[new_obj] += (f32)
    mconv_kernel<1, 1, false, 2, bf16, float><<<dim3(1024), dim3(TPB), 0, stream>>>(
        v1, nullptr, nullptr, wbob, bob, out, nullptr, nullptr, 128, 128);
}